// Round 3
// baseline (3139.628 us; speedup 1.0000x reference)
//
#include <hip/hip_runtime.h>
#include <math.h>

// Problem constants (from reference setup_inputs)
#define BB 16
#define DD 40
#define NN 64512
#define KK 4

#define ALPHA 5.0f
#define N_ITERS 10
#define EPS_KM 1e-9f

__device__ __forceinline__ void fma4s(float4& a, float s, const float4& v) {
    a.x = fmaf(s, v.x, a.x);
    a.y = fmaf(s, v.y, a.y);
    a.z = fmaf(s, v.z, a.z);
    a.w = fmaf(s, v.w, a.w);
}
__device__ __forceinline__ void fma4sq(float4& a, const float4& v) {
    a.x = fmaf(v.x, v.x, a.x);
    a.y = fmaf(v.y, v.y, a.y);
    a.z = fmaf(v.z, v.z, a.z);
    a.w = fmaf(v.w, v.w, a.w);
}
__device__ __forceinline__ float dot4acc(float acc, const float4& y, const float4& v) {
    return fmaf(y.x, v.x, fmaf(y.y, v.y, fmaf(y.z, v.z, fmaf(y.w, v.w, acc))));
}

// ---------------------------------------------------------------------------
// Kernel 1: Vact = tanh(V), vectorized float4.
// ---------------------------------------------------------------------------
__global__ __launch_bounds__(256) void tanh_kernel(const float4* __restrict__ V,
                                                   float4* __restrict__ Vact,
                                                   int n4) {
    int i = blockIdx.x * 256 + threadIdx.x;
    if (i < n4) {
        float4 x = V[i];
        float4 y;
        y.x = tanhf(x.x);
        y.y = tanhf(x.y);
        y.z = tanhf(x.z);
        y.w = tanhf(x.w);
        Vact[i] = y;
    }
}

// ---------------------------------------------------------------------------
// Kernel 2: init U0[b,k,d] = tanh(V[b,d,idx[b,k]]); compute u2; zero accums.
// ---------------------------------------------------------------------------
__global__ __launch_bounds__(256) void init_kernel(const float* __restrict__ V,
                                                   const int* __restrict__ idx,
                                                   float* __restrict__ U,
                                                   float* __restrict__ accV,
                                                   float* __restrict__ accS,
                                                   float* __restrict__ u2) {
    const int tid = threadIdx.x;
    for (int i = tid; i < BB * KK * DD; i += 256) {
        int b = i / (KK * DD);
        int r = i - b * (KK * DD);
        int k = r / DD;
        int d = r - k * DD;
        int n0 = idx[b * KK + k];
        U[i] = tanhf(V[(b * DD + d) * NN + n0]);
        accV[i] = 0.f;
    }
    __syncthreads();
    if (tid < BB * KK) {
        float s = 0.f;
        for (int d = 0; d < DD; ++d) {
            float x = U[tid * DD + d];
            s = fmaf(x, x, s);
        }
        u2[tid] = s;
        accS[tid] = 0.f;
    }
}

// ---------------------------------------------------------------------------
// Kernel 3: one k-means iteration — 3-phase block design, float4 streaming.
//
// Block = 256 threads (4 waves), owns NPB=512 consecutive n of one batch b.
// Wave w owns d-slice [10w, 10w+10). Lane l owns 4 consecutive points per
// step: p0 = s*256 + 4l. All global loads are dwordx4 (1 KB per wave-instr,
// 10 independent per step, 2 steps per phase -> 10 KB in flight per wave).
//
// Phase 1: partial dot products (pc[k], pv) for the wave's 10 d's, written
//   to LDS pp[w*5+c][NPB] as float4 (conflict-free).
// Phase 2 (1 barrier): wave w softmaxes its 128-n quarter from summed
//   partials; y to LDS; wave-reduced sum_y -> atomicAdd accS.
// Phase 3 (1 barrier): reload v (L2-hot), read y (b128), accumulate
//   acc[4][10] in registers.
// Epilogue: pad-41 LDS transpose reduce across lanes; 160 atomicAdds/block.
// Centroids are read through an LDS [d][k] table via broadcast b128 reads
// (saves 40 VGPRs vs register-resident uk[4][10]).
// ---------------------------------------------------------------------------
#define NPB 512            // n per block
#define GX (NN / NPB)      // 126

__global__ __launch_bounds__(256) void km_iter_kernel(const float* __restrict__ Vact,
                                                      const float* __restrict__ U,
                                                      const float* __restrict__ u2,
                                                      float* __restrict__ accV,
                                                      float* __restrict__ accS) {
    __shared__ float smem[24 * NPB + 192];  // pp[20][NPB] + yy[4][NPB] + sUd[160]
    float (*pp)[NPB] = (float (*)[NPB])smem;
    float (*yy)[NPB] = (float (*)[NPB])(smem + 20 * NPB);
    float* sUd = smem + 24 * NPB;  // layout [d][k]: sUd[d*4+k]

    const int tid = threadIdx.x;
    const int w = tid >> 6;   // wave id 0..3, owns d in [10w, 10w+10)
    const int l = tid & 63;
    const int b = blockIdx.y;
    const int d0 = w * 10;
    const int nb = blockIdx.x * NPB;

    const float* Vb = Vact + (size_t)b * (size_t)(DD * NN);
    const float* Ub = U + b * (KK * DD);

    if (tid < KK * DD) {
        const int d = tid >> 2;
        const int k = tid & 3;
        sUd[tid] = Ub[k * DD + d];
    }
    __syncthreads();

    // ---------------- Phase 1: partial dot products (float4 points) ----------
#pragma unroll
    for (int s = 0; s < NPB / 256; ++s) {
        const int p0 = s * 256 + 4 * l;
        float4 v[10];
#pragma unroll
        for (int j = 0; j < 10; ++j)
            v[j] = *(const float4*)(Vb + (size_t)(d0 + j) * NN + nb + p0);

        float4 c0 = {0,0,0,0}, c1 = {0,0,0,0}, c2 = {0,0,0,0}, c3 = {0,0,0,0};
        float4 q  = {0,0,0,0};
#pragma unroll
        for (int j = 0; j < 10; ++j) {
            const float4 u4 = *(const float4*)&sUd[(d0 + j) * 4];  // broadcast
            fma4sq(q, v[j]);
            fma4s(c0, u4.x, v[j]);
            fma4s(c1, u4.y, v[j]);
            fma4s(c2, u4.z, v[j]);
            fma4s(c3, u4.w, v[j]);
        }
        *(float4*)&pp[w * 5 + 0][p0] = c0;
        *(float4*)&pp[w * 5 + 1][p0] = c1;
        *(float4*)&pp[w * 5 + 2][p0] = c2;
        *(float4*)&pp[w * 5 + 3][p0] = c3;
        *(float4*)&pp[w * 5 + 4][p0] = q;
    }
    __syncthreads();

    // ---------------- Phase 2: softmax for this wave's n-quarter -------------
    float u2r[KK];
#pragma unroll
    for (int k = 0; k < KK; ++k) u2r[k] = u2[b * KK + k];

    float sy[KK] = {0.f, 0.f, 0.f, 0.f};
#pragma unroll
    for (int s2 = 0; s2 < NPB / 256; ++s2) {
        const int nl = w * (NPB / 4) + s2 * 64 + l;
        float cc[KK];
#pragma unroll
        for (int k = 0; k < KK; ++k)
            cc[k] = pp[k][nl] + pp[5 + k][nl] + pp[10 + k][nl] + pp[15 + k][nl];
        const float v2 = pp[4][nl] + pp[9][nl] + pp[14][nl] + pp[19][nl];

        float dist[KK];
        float m = -1e30f;
#pragma unroll
        for (int k = 0; k < KK; ++k) {
            float d2 = fmaf(-2.f, cc[k], v2 + u2r[k]);
            dist[k] = -ALPHA * sqrtf(fmaxf(d2, 1e-12f));
            m = fmaxf(m, dist[k]);
        }
        float e[KK];
        float se = 0.f;
#pragma unroll
        for (int k = 0; k < KK; ++k) {
            e[k] = expf(dist[k] - m);
            se += e[k];
        }
        const float inv = 1.f / se;
#pragma unroll
        for (int k = 0; k < KK; ++k) {
            const float y = e[k] * inv;
            yy[k][nl] = y;
            sy[k] += y;
        }
    }
#pragma unroll
    for (int k = 0; k < KK; ++k) {
        float sv = sy[k];
        for (int off = 32; off > 0; off >>= 1) sv += __shfl_down(sv, off, 64);
        if (l == 0) atomicAdd(&accS[b * KK + k], sv);
    }
    __syncthreads();

    // ---------------- Phase 3: accumulate y * v (float4 points) --------------
    float acc[KK][10];
#pragma unroll
    for (int k = 0; k < KK; ++k)
#pragma unroll
        for (int j = 0; j < 10; ++j) acc[k][j] = 0.f;

#pragma unroll
    for (int s = 0; s < NPB / 256; ++s) {
        const int p0 = s * 256 + 4 * l;
        float4 v[10];
#pragma unroll
        for (int j = 0; j < 10; ++j)
            v[j] = *(const float4*)(Vb + (size_t)(d0 + j) * NN + nb + p0);
        const float4 y0 = *(const float4*)&yy[0][p0];
        const float4 y1 = *(const float4*)&yy[1][p0];
        const float4 y2 = *(const float4*)&yy[2][p0];
        const float4 y3 = *(const float4*)&yy[3][p0];
#pragma unroll
        for (int j = 0; j < 10; ++j) {
            acc[0][j] = dot4acc(acc[0][j], y0, v[j]);
            acc[1][j] = dot4acc(acc[1][j], y1, v[j]);
            acc[2][j] = dot4acc(acc[2][j], y2, v[j]);
            acc[3][j] = dot4acc(acc[3][j], y3, v[j]);
        }
    }
    __syncthreads();  // everyone done reading yy/pp before scratch reuse

    // ---------------- Epilogue: LDS-transpose reduce (stride 41) -------------
    float* wr = smem + w * (64 * 41);  // 4*2624 = 10496 <= 12288 floats
#pragma unroll
    for (int k = 0; k < KK; ++k)
#pragma unroll
        for (int j = 0; j < 10; ++j) wr[l * 41 + k * 10 + j] = acc[k][j];
    __syncthreads();

    if (l < KK * 10) {
        float s = 0.f;
        for (int l2 = 0; l2 < 64; ++l2) s += wr[l2 * 41 + l];
        const int k = l / 10;
        const int j = l - k * 10;
        atomicAdd(&accV[b * KK * DD + k * DD + d0 + j], s);
    }
}

// ---------------------------------------------------------------------------
// Kernel 4: finalize U = accV/(accS+eps); recompute u2; zero accums.
// ---------------------------------------------------------------------------
__global__ __launch_bounds__(256) void km_finalize_kernel(float* __restrict__ U,
                                                          float* __restrict__ accV,
                                                          float* __restrict__ accS,
                                                          float* __restrict__ u2) {
    const int tid = threadIdx.x;
    for (int i = tid; i < BB * KK * DD; i += 256) {
        U[i] = accV[i] / (accS[i / DD] + EPS_KM);
        accV[i] = 0.f;
    }
    __syncthreads();
    if (tid < BB * KK) {
        float s = 0.f;
        for (int d = 0; d < DD; ++d) {
            float x = U[tid * DD + d];
            s = fmaf(x, x, s);
        }
        u2[tid] = s;
        accS[tid] = 0.f;
    }
}

// ---------------------------------------------------------------------------
// Kernel 5: final mask = softmax_k( A . Vact ), float4 points.
// grid = (63, B), 256 thr; lane handles 4 consecutive n.
// ---------------------------------------------------------------------------
__global__ __launch_bounds__(256) void mask_kernel(const float* __restrict__ Vact,
                                                   const float* __restrict__ U,
                                                   float* __restrict__ mask) {
    __shared__ float sA[KK * DD];
    const int tid = threadIdx.x;
    const int b = blockIdx.y;
    const int n0 = blockIdx.x * 1024 + 4 * tid;

    for (int i = tid; i < KK * DD; i += 256) sA[i] = U[b * KK * DD + i];
    __syncthreads();

    const float* Vb = Vact + (size_t)b * (size_t)(DD * NN);
    float4 dk0 = {0,0,0,0}, dk1 = {0,0,0,0}, dk2 = {0,0,0,0}, dk3 = {0,0,0,0};
    for (int d = 0; d < DD; ++d) {
        const float4 vv = *(const float4*)(Vb + (size_t)d * NN + n0);
        fma4s(dk0, sA[0 * DD + d], vv);
        fma4s(dk1, sA[1 * DD + d], vv);
        fma4s(dk2, sA[2 * DD + d], vv);
        fma4s(dk3, sA[3 * DD + d], vv);
    }
    float4 m;
    m.x = fmaxf(fmaxf(dk0.x, dk1.x), fmaxf(dk2.x, dk3.x));
    m.y = fmaxf(fmaxf(dk0.y, dk1.y), fmaxf(dk2.y, dk3.y));
    m.z = fmaxf(fmaxf(dk0.z, dk1.z), fmaxf(dk2.z, dk3.z));
    m.w = fmaxf(fmaxf(dk0.w, dk1.w), fmaxf(dk2.w, dk3.w));
    float4 e0, e1, e2, e3, inv;
    e0.x = expf(dk0.x - m.x); e0.y = expf(dk0.y - m.y); e0.z = expf(dk0.z - m.z); e0.w = expf(dk0.w - m.w);
    e1.x = expf(dk1.x - m.x); e1.y = expf(dk1.y - m.y); e1.z = expf(dk1.z - m.z); e1.w = expf(dk1.w - m.w);
    e2.x = expf(dk2.x - m.x); e2.y = expf(dk2.y - m.y); e2.z = expf(dk2.z - m.z); e2.w = expf(dk2.w - m.w);
    e3.x = expf(dk3.x - m.x); e3.y = expf(dk3.y - m.y); e3.z = expf(dk3.z - m.z); e3.w = expf(dk3.w - m.w);
    inv.x = 1.f / (e0.x + e1.x + e2.x + e3.x);
    inv.y = 1.f / (e0.y + e1.y + e2.y + e3.y);
    inv.z = 1.f / (e0.z + e1.z + e2.z + e3.z);
    inv.w = 1.f / (e0.w + e1.w + e2.w + e3.w);
    e0.x *= inv.x; e0.y *= inv.y; e0.z *= inv.z; e0.w *= inv.w;
    e1.x *= inv.x; e1.y *= inv.y; e1.z *= inv.z; e1.w *= inv.w;
    e2.x *= inv.x; e2.y *= inv.y; e2.z *= inv.z; e2.w *= inv.w;
    e3.x *= inv.x; e3.y *= inv.y; e3.z *= inv.z; e3.w *= inv.w;
    float* mb = mask + (size_t)b * (size_t)(KK * NN);
    *(float4*)(mb + 0 * NN + n0) = e0;
    *(float4*)(mb + 1 * NN + n0) = e1;
    *(float4*)(mb + 2 * NN + n0) = e2;
    *(float4*)(mb + 3 * NN + n0) = e3;
}

// ---------------------------------------------------------------------------
// Kernel 6: copy A (=U after 10 iters) to the output tail.
// ---------------------------------------------------------------------------
__global__ __launch_bounds__(256) void copyA_kernel(const float* __restrict__ U,
                                                    float* __restrict__ Aout) {
    int i = blockIdx.x * 256 + threadIdx.x;
    if (i < BB * KK * DD) Aout[i] = U[i];
}

// ---------------------------------------------------------------------------
extern "C" void kernel_launch(void* const* d_in, const int* in_sizes, int n_in,
                              void* d_out, int out_size, void* d_ws, size_t ws_size,
                              hipStream_t stream) {
    const float* V = (const float*)d_in[0];
    const int* idx = (const int*)d_in[1];

    float* out = (float*)d_out;
    float* mask = out;                                   // B*K*N
    float* Vact = out + (size_t)BB * KK * NN;            // B*D*N
    float* Aout = Vact + (size_t)BB * DD * NN;           // B*K*D

    float* ws = (float*)d_ws;
    float* U    = ws;            // 2560
    float* accV = ws + 2560;     // 2560
    float* accS = ws + 5120;     // 64
    float* u2   = ws + 5184;     // 64

    const int n4 = (BB * DD * NN) / 4;  // 10321920
    tanh_kernel<<<dim3((n4 + 255) / 256), dim3(256), 0, stream>>>(
        (const float4*)V, (float4*)Vact, n4);
    init_kernel<<<dim3(1), dim3(256), 0, stream>>>(V, idx, U, accV, accS, u2);

    for (int it = 0; it < N_ITERS; ++it) {
        km_iter_kernel<<<dim3(GX, BB), dim3(256), 0, stream>>>(Vact, U, u2, accV, accS);
        km_finalize_kernel<<<dim3(1), dim3(256), 0, stream>>>(U, accV, accS, u2);
    }

    mask_kernel<<<dim3(NN / 1024, BB), dim3(256), 0, stream>>>(Vact, U, mask);
    copyA_kernel<<<dim3(10), dim3(256), 0, stream>>>(U, Aout);
}